// Round 5
// baseline (133.928 us; speedup 1.0000x reference)
//
#include <hip/hip_runtime.h>

#define SQ 1024
#define DM 1024
#define HD 64
#define NBH 64   // BATCH*NH

typedef __attribute__((ext_vector_type(8))) _Float16 v8h;
typedef __attribute__((ext_vector_type(4))) float v4f;
typedef __attribute__((ext_vector_type(2))) __fp16 v2fp16;
typedef __attribute__((ext_vector_type(2))) unsigned int v2u;
typedef __attribute__((ext_vector_type(4))) unsigned int v4u;

__device__ __forceinline__ v4f mfma_f16(v8h a, v8h b, v4f c) {
  return __builtin_amdgcn_mfma_f32_16x16x32_f16(a, b, c, 0, 0, 0);
}

// Build fp16 Q, K' = 0.125*k + rel_k[s], and transposed V'^T where V' = v + rel_v[s].
// Layouts: Qh/Kh: [bh][s][d] (d contiguous, 64), Vth: [bh][d][s] (s contiguous, 1024).
__global__ __launch_bounds__(256) void prep_kernel(
    const float* __restrict__ q, const float* __restrict__ k, const float* __restrict__ v,
    const float* __restrict__ relk, const float* __restrict__ relv,
    _Float16* __restrict__ Qh, _Float16* __restrict__ Kh,
    _Float16* __restrict__ Vth)
{
  __shared__ float vt[64][65];
  int blk = blockIdx.x;            // bh*16 + stile
  int st = blk & 15;
  int bh = blk >> 4;
  int b = bh >> 4, h = bh & 15;
  int s0 = st * 64;
  int t = (int)threadIdx.x;
  int d = t & 63, sl4 = t >> 6;    // 0..3
  const float scale = 0.125f;

  #pragma unroll
  for (int i = 0; i < 16; ++i) {
    int sl = sl4 + i * 4;
    int s = s0 + sl;
    size_t gidx = ((size_t)(b * SQ + s)) * DM + h * HD + d;
    float qv = q[gidx];
    float kv = k[gidx] * scale + relk[s * HD + d];
    float vv = v[gidx] + relv[s * HD + d];
    size_t widx = ((size_t)(bh * SQ + s)) * HD + d;
    Qh[widx] = (_Float16)qv;
    Kh[widx] = (_Float16)kv;
    vt[sl][d] = vv;
  }
  __syncthreads();
  int sl = t & 63, d4 = t >> 6;
  #pragma unroll
  for (int i = 0; i < 16; ++i) {
    int dd = d4 + i * 4;
    Vth[((size_t)(bh * HD + dd)) * SQ + s0 + sl] = (_Float16)vt[sl][dd];
  }
}

// Flash attention fwd, swapped-operand form, NO K/V LDS staging (L2-direct).
// 1D grid 1024 blocks (XCD-swizzled), 256 threads = 4 waves, wave owns 16 q rows.
// S^T = K'.Q^T -> lane holds 16 scores of ONE q-row (q = lane&15).
// O^T = V'^T.P -> lane holds 16 outputs of that q-row, d contiguous per acc reg.
__global__ __launch_bounds__(256) void attn_kernel(
    const _Float16* __restrict__ Qh, const _Float16* __restrict__ Kh,
    const _Float16* __restrict__ Vth, float* __restrict__ out)
{
  __shared__ __align__(16) unsigned int Pl[4][16][36];  // per-wave packed-fp16 P

  int tid = (int)threadIdx.x;
  int lane = tid & 63, w = tid >> 6;
  int g = lane >> 4, r15 = lane & 15;
  // bijective XCD swizzle: 1024 blocks = 8 XCDs x 128; each XCD owns 8 full bh
  int bid = (int)blockIdx.x;
  int wk = (bid & 7) * 128 + (bid >> 3);
  int qt = wk & 15, bh = wk >> 4;
  int b = bh >> 4, h = bh & 15;
  int qrow = qt * 64 + w * 16 + r15;

  // Q as B-fragment: col = q = lane&15, k-dim d = 8*(lane>>4)+j
  const _Float16* qbase = Qh + ((size_t)(bh * SQ + qrow)) * HD;
  v8h aq0 = *(const v8h*)(qbase + g * 8);
  v8h aq1 = *(const v8h*)(qbase + 32 + g * 8);

  const _Float16* kb = Kh + (size_t)bh * SQ * HD;
  const _Float16* vb = Vth + (size_t)bh * HD * SQ;

  v4f o[4];
  #pragma unroll
  for (int c = 0; c < 4; ++c) o[c] = (v4f){0.f, 0.f, 0.f, 0.f};
  float m = -3.0e38f, l = 0.f;

  for (int t0 = 0; t0 < SQ / 64; ++t0) {
    int k0 = t0 * 64;

    // ---- K' fragments direct from global (L2): A[row=k][col=d] ----
    v8h kf0[4], kf1[4];
    #pragma unroll
    for (int c = 0; c < 4; ++c) {
      const _Float16* kr = kb + ((size_t)(k0 + c * 16 + r15)) * HD;
      kf0[c] = *(const v8h*)(kr + g * 8);
      kf1[c] = *(const v8h*)(kr + 32 + g * 8);
    }

    // ---- S^T = K'.Q^T : sacc[c][r] = S[q=r15][k = 16c + 4g + r] ----
    v4f sacc[4];
    #pragma unroll
    for (int c = 0; c < 4; ++c) {
      v4f z = (v4f){0.f, 0.f, 0.f, 0.f};
      z = mfma_f16(kf0[c], aq0, z);
      z = mfma_f16(kf1[c], aq1, z);
      sacc[c] = z;
    }

    // ---- V'^T fragments issued now; latency hides under softmax ----
    v8h vf0[4], vf1[4];
    #pragma unroll
    for (int c = 0; c < 4; ++c) {
      const _Float16* vr = vb + ((size_t)(c * 16 + r15)) * SQ + k0;
      vf0[c] = *(const v8h*)(vr + g * 8);
      vf1[c] = *(const v8h*)(vr + 32 + g * 8);
    }

    // ---- online softmax with defer-max (T13, THR=8) ----
    float pm = sacc[0][0];
    #pragma unroll
    for (int c = 0; c < 4; ++c)
      #pragma unroll
      for (int r = 0; r < 4; ++r)
        pm = fmaxf(pm, sacc[c][r]);
    pm = fmaxf(pm, __shfl_xor(pm, 16));
    pm = fmaxf(pm, __shfl_xor(pm, 32));
    if (!__all(pm - m <= 8.f)) {
      float mnew = fmaxf(m, pm);
      float sc = __expf(m - mnew);
      m = mnew;
      l *= sc;
      #pragma unroll
      for (int c = 0; c < 4; ++c) o[c] *= sc;
    }
    float rs = 0.f;
    #pragma unroll
    for (int c = 0; c < 4; ++c)
      #pragma unroll
      for (int r = 0; r < 4; ++r) {
        float p = __expf(sacc[c][r] - m);
        sacc[c][r] = p;
        rs += p;
      }
    rs += __shfl_xor(rs, 16);
    rs += __shfl_xor(rs, 32);
    l += rs;

    // ---- pack P to fp16, redistribute via tiny per-wave LDS ----
    // lane holds k = 16c+4g+{0..3} -> words 8c+2g+{0,1}
    #pragma unroll
    for (int c = 0; c < 4; ++c) {
      v2fp16 p01 = __builtin_amdgcn_cvt_pkrtz(sacc[c][0], sacc[c][1]);
      v2fp16 p23 = __builtin_amdgcn_cvt_pkrtz(sacc[c][2], sacc[c][3]);
      v2u pack;
      pack[0] = __builtin_bit_cast(unsigned int, p01);
      pack[1] = __builtin_bit_cast(unsigned int, p23);
      *(v2u*)(&Pl[w][r15][8 * c + 2 * g]) = pack;
    }
    // same-wave write->read on aliasing LDS: compiler orders + waits lgkmcnt
    v8h pb0 = __builtin_bit_cast(v8h, *(const v4u*)(&Pl[w][r15][4 * g]));
    v8h pb1 = __builtin_bit_cast(v8h, *(const v4u*)(&Pl[w][r15][16 + 4 * g]));

    // ---- O^T += V'^T . P : o[c][r] = O[q=r15][d = 16c + 4g + r] ----
    #pragma unroll
    for (int c = 0; c < 4; ++c) {
      o[c] = mfma_f16(vf0[c], pb0, o[c]);
      o[c] = mfma_f16(vf1[c], pb1, o[c]);
    }
  }

  // ---- epilogue: normalize, vectorized stores (d contiguous within o[c]) ----
  float inv = 1.f / l;
  #pragma unroll
  for (int c = 0; c < 4; ++c) {
    v4f res = o[c] * inv;
    *(v4f*)(&out[((size_t)(b * SQ + qrow)) * DM + h * HD + 16 * c + 4 * g]) = res;
  }
}

extern "C" void kernel_launch(void* const* d_in, const int* in_sizes, int n_in,
                              void* d_out, int out_size, void* d_ws, size_t ws_size,
                              hipStream_t stream) {
  const float* q = (const float*)d_in[0];
  const float* k = (const float*)d_in[1];
  const float* v = (const float*)d_in[2];
  const float* relk = (const float*)d_in[3];
  const float* relv = (const float*)d_in[4];

  _Float16* Qh = (_Float16*)d_ws;
  _Float16* Kh = Qh + (size_t)NBH * SQ * HD;
  _Float16* Vth = Kh + (size_t)NBH * SQ * HD;

  prep_kernel<<<dim3(NBH * (SQ / 64)), dim3(256), 0, stream>>>(q, k, v, relk, relv, Qh, Kh, Vth);
  attn_kernel<<<dim3(1024), dim3(256), 0, stream>>>(Qh, Kh, Vth, (float*)d_out);
}

// Round 6
// 50.162 us; speedup vs baseline: 2.6699x; 2.6699x over previous
//
#include <hip/hip_runtime.h>

#define SQ 1024
#define DM 1024
#define HD 64
#define NBH 64   // BATCH*NH

typedef __attribute__((ext_vector_type(8))) _Float16 v8h;
typedef __attribute__((ext_vector_type(4))) float v4f;
typedef __attribute__((ext_vector_type(2))) __fp16 v2fp16;
typedef __attribute__((ext_vector_type(4))) unsigned int v4u;

__device__ __forceinline__ v4f mfma_f16(v8h a, v8h b, v4f c) {
  return __builtin_amdgcn_mfma_f32_16x16x32_f16(a, b, c, 0, 0, 0);
}

// Build fp16 Q, K' = 0.125*k + rel_k[s], and transposed V'^T where V' = v + rel_v[s].
// Layouts: Qh/Kh: [bh][s][d] (d contiguous, 64), Vth: [bh][d][s] (s contiguous, 1024).
__global__ __launch_bounds__(256) void prep_kernel(
    const float* __restrict__ q, const float* __restrict__ k, const float* __restrict__ v,
    const float* __restrict__ relk, const float* __restrict__ relv,
    _Float16* __restrict__ Qh, _Float16* __restrict__ Kh,
    _Float16* __restrict__ Vth)
{
  __shared__ float vt[64][65];
  int blk = blockIdx.x;            // bh*16 + stile
  int st = blk & 15;
  int bh = blk >> 4;
  int b = bh >> 4, h = bh & 15;
  int s0 = st * 64;
  int t = (int)threadIdx.x;
  int d = t & 63, sl4 = t >> 6;    // 0..3
  const float scale = 0.125f;

  #pragma unroll
  for (int i = 0; i < 16; ++i) {
    int sl = sl4 + i * 4;
    int s = s0 + sl;
    size_t gidx = ((size_t)(b * SQ + s)) * DM + h * HD + d;
    float qv = q[gidx];
    float kv = k[gidx] * scale + relk[s * HD + d];
    float vv = v[gidx] + relv[s * HD + d];
    size_t widx = ((size_t)(bh * SQ + s)) * HD + d;
    Qh[widx] = (_Float16)qv;
    Kh[widx] = (_Float16)kv;
    vt[sl][d] = vv;
  }
  __syncthreads();
  int sl = t & 63, d4 = t >> 6;
  #pragma unroll
  for (int i = 0; i < 16; ++i) {
    int dd = d4 + i * 4;
    Vth[((size_t)(bh * HD + dd)) * SQ + s0 + sl] = (_Float16)vt[sl][dd];
  }
}

// Flash attention fwd. Grid 512 blocks (XCD-swizzled: 8 XCDs x 64), 4 waves/block.
// Wave owns 32 q-rows (2 groups of 16). KV tiles of 64, LDS-staged with XOR
// granule swizzle (conflict-free). QK^T uses a permuted A-row -> k mapping so
// the S^T accumulator is ALREADY in PV B-fragment layout: no P LDS roundtrip.
__global__ __launch_bounds__(256) void attn_kernel(
    const _Float16* __restrict__ Qh, const _Float16* __restrict__ Kh,
    const _Float16* __restrict__ Vth, float* __restrict__ out)
{
  // granule (row, gr) stored at physical granule row*8 + (gr ^ f(row)),
  // f(row) = (row&3) | ((row>>3 & 1) << 2)
  __shared__ v8h KlG[64 * 8];   // K' tile  [krow][d]  8KB
  __shared__ v8h VlG[64 * 8];   // V'^T tile [d][kcol] 8KB

  int tid = (int)threadIdx.x;
  int lane = tid & 63, w = tid >> 6;
  int g = lane >> 4, r15 = lane & 15;
  // bijective XCD swizzle: 512 = 8 XCDs x 64; each XCD gets 8 whole bh (2MB KV < 4MB L2)
  int bid = (int)blockIdx.x;
  int wk = (bid & 7) * 64 + (bid >> 3);
  int bh = wk >> 3, qt = wk & 7;
  int b = bh >> 4, h = bh & 15;
  int q0 = qt * 128 + w * 32;

  // Q B-frags for 2 groups: col=q=r15, contraction d = 8g+j (+32 for [1])
  v8h aq[2][2];
  #pragma unroll
  for (int t = 0; t < 2; ++t) {
    const _Float16* qb = Qh + ((size_t)(bh * SQ + q0 + 16 * t + r15)) * HD;
    aq[t][0] = *(const v8h*)(qb + g * 8);
    aq[t][1] = *(const v8h*)(qb + 32 + g * 8);
  }

  const _Float16* kb = Kh + (size_t)bh * SQ * HD;
  const _Float16* vb = Vth + (size_t)bh * HD * SQ;

  v4f o[2][4];
  #pragma unroll
  for (int t = 0; t < 2; ++t)
    #pragma unroll
    for (int c = 0; c < 4; ++c) o[t][c] = (v4f){0.f, 0.f, 0.f, 0.f};
  float m[2] = {-3.0e38f, -3.0e38f}, l[2] = {0.f, 0.f};

  // K-frag read rows (permuted): A-row r15 of chunk c holds K-row krow[c]
  // k_phys(c,m) = 32*(c>>1) + 8*(m>>2) + 4*(c&1) + (m&3), m = r15
  int krow[4];
  #pragma unroll
  for (int c = 0; c < 4; ++c)
    krow[c] = ((c >> 1) << 5) + ((r15 >> 2) << 3) + ((c & 1) << 2) + (r15 & 3);
  int fk = (r15 & 3) | (((r15 >> 2) & 1) << 2);   // f(krow[c]) for all c
  int fv = (r15 & 3) | (((r15 >> 3) & 1) << 2);   // f(16c + r15) for all c

  for (int t0 = 0; t0 < SQ / 64; ++t0) {
    int k0 = t0 * 64;
    if (t0) __syncthreads();
    // ---- stage K' and V'^T tiles (conflict-free swizzled writes) ----
    #pragma unroll
    for (int i = 0; i < 2; ++i) {
      int seg = tid + i * 256;
      int row = seg >> 3, gr = seg & 7;
      int fs = (row & 3) | (((row >> 3) & 1) << 2);
      v8h kd = *(const v8h*)(kb + ((size_t)(k0 + row)) * HD + gr * 8);
      v8h vd = *(const v8h*)(vb + ((size_t)row) * SQ + k0 + gr * 8);
      KlG[row * 8 + (gr ^ fs)] = kd;
      VlG[row * 8 + (gr ^ fs)] = vd;
    }
    __syncthreads();

    // ---- S^T = K'.Q^T with permuted k rows; s[t][c][r] = P-pre[q=r15][k_phys(c,4g+r)] ----
    v4f s[2][4];
    #pragma unroll
    for (int c = 0; c < 4; ++c) {
      v8h kf0 = KlG[krow[c] * 8 + (g ^ fk)];
      v8h kf1 = KlG[krow[c] * 8 + ((4 | g) ^ fk)];
      v4f z0 = (v4f){0.f, 0.f, 0.f, 0.f};
      v4f z1 = (v4f){0.f, 0.f, 0.f, 0.f};
      z0 = mfma_f16(kf0, aq[0][0], z0);
      z0 = mfma_f16(kf1, aq[0][1], z0);
      z1 = mfma_f16(kf0, aq[1][0], z1);
      z1 = mfma_f16(kf1, aq[1][1], z1);
      s[0][c] = z0;
      s[1][c] = z1;
    }

    // ---- online softmax, defer-max (T13), per-lane l partials: no shuffles in common path ----
    #pragma unroll
    for (int t = 0; t < 2; ++t) {
      float pm = s[t][0][0];
      #pragma unroll
      for (int c = 0; c < 4; ++c)
        #pragma unroll
        for (int r = 0; r < 4; ++r)
          pm = fmaxf(pm, s[t][c][r]);
      if (!__all(pm - m[t] <= 8.f)) {
        pm = fmaxf(pm, __shfl_xor(pm, 16));
        pm = fmaxf(pm, __shfl_xor(pm, 32));
        float mnew = fmaxf(m[t], pm);
        float sc = __expf(m[t] - mnew);
        m[t] = mnew;
        l[t] *= sc;
        #pragma unroll
        for (int c = 0; c < 4; ++c) o[t][c] *= sc;
      }
      float rs = 0.f;
      #pragma unroll
      for (int c = 0; c < 4; ++c)
        #pragma unroll
        for (int r = 0; r < 4; ++r) {
          float p = __expf(s[t][c][r] - m[t]);
          s[t][c][r] = p;
          rs += p;
        }
      l[t] += rs;
    }

    // ---- pack P in-lane: acc IS the PV B-frag layout (k-slot 8g+j / 32+8g+j) ----
    v8h pb0[2], pb1[2];
    #pragma unroll
    for (int t = 0; t < 2; ++t) {
      v4u w0, w1;
      w0[0] = __builtin_bit_cast(unsigned int, __builtin_amdgcn_cvt_pkrtz(s[t][0][0], s[t][0][1]));
      w0[1] = __builtin_bit_cast(unsigned int, __builtin_amdgcn_cvt_pkrtz(s[t][0][2], s[t][0][3]));
      w0[2] = __builtin_bit_cast(unsigned int, __builtin_amdgcn_cvt_pkrtz(s[t][1][0], s[t][1][1]));
      w0[3] = __builtin_bit_cast(unsigned int, __builtin_amdgcn_cvt_pkrtz(s[t][1][2], s[t][1][3]));
      w1[0] = __builtin_bit_cast(unsigned int, __builtin_amdgcn_cvt_pkrtz(s[t][2][0], s[t][2][1]));
      w1[1] = __builtin_bit_cast(unsigned int, __builtin_amdgcn_cvt_pkrtz(s[t][2][2], s[t][2][3]));
      w1[2] = __builtin_bit_cast(unsigned int, __builtin_amdgcn_cvt_pkrtz(s[t][3][0], s[t][3][1]));
      w1[3] = __builtin_bit_cast(unsigned int, __builtin_amdgcn_cvt_pkrtz(s[t][3][2], s[t][3][3]));
      pb0[t] = __builtin_bit_cast(v8h, w0);
      pb1[t] = __builtin_bit_cast(v8h, w1);
    }

    // ---- O^T += V'^T . P (V frags shared across both groups) ----
    #pragma unroll
    for (int c = 0; c < 4; ++c) {
      int rv = 16 * c + r15;
      v8h vf0 = VlG[rv * 8 + (g ^ fv)];
      v8h vf1 = VlG[rv * 8 + ((4 | g) ^ fv)];
      #pragma unroll
      for (int t = 0; t < 2; ++t) {
        o[t][c] = mfma_f16(vf0, pb0[t], o[t][c]);
        o[t][c] = mfma_f16(vf1, pb1[t], o[t][c]);
      }
    }
  }

  // ---- epilogue: quad-reduce l, normalize, vectorized stores ----
  #pragma unroll
  for (int t = 0; t < 2; ++t) {
    float lr = l[t];
    lr += __shfl_xor(lr, 16);
    lr += __shfl_xor(lr, 32);
    float inv = 1.f / lr;
    int qrow = q0 + 16 * t + r15;
    #pragma unroll
    for (int c = 0; c < 4; ++c) {
      v4f res = o[t][c] * inv;
      *(v4f*)(&out[((size_t)(b * SQ + qrow)) * DM + h * HD + 16 * c + 4 * g]) = res;
    }
  }
}

extern "C" void kernel_launch(void* const* d_in, const int* in_sizes, int n_in,
                              void* d_out, int out_size, void* d_ws, size_t ws_size,
                              hipStream_t stream) {
  const float* q = (const float*)d_in[0];
  const float* k = (const float*)d_in[1];
  const float* v = (const float*)d_in[2];
  const float* relk = (const float*)d_in[3];
  const float* relv = (const float*)d_in[4];

  _Float16* Qh = (_Float16*)d_ws;
  _Float16* Kh = Qh + (size_t)NBH * SQ * HD;
  _Float16* Vth = Kh + (size_t)NBH * SQ * HD;

  prep_kernel<<<dim3(NBH * (SQ / 64)), dim3(256), 0, stream>>>(q, k, v, relk, relv, Qh, Kh, Vth);
  attn_kernel<<<dim3(512), dim3(256), 0, stream>>>(Qh, Kh, Vth, (float*)d_out);
}